// Round 10
// baseline (262.975 us; speedup 1.0000x reference)
//
#include <hip/hip_runtime.h>

#define N_NODES_C   50000
#define N_EDGES_C   1600000
#define FEAT        128
#define NREL        8
#define NBUCKETS    400000
#define KTOT        1024
#define TILE        16                 // nodes per block; 50000 = 3125*16 exactly

// ---------------- workspace layout (bytes) ----------------
#define WS_COUNTS   0          // u32[100000] (u8x4 packed)     400,000
#define WS_OFFSETS  400000     // u32[400001] (+sentinel)     1,600,016
#define WS_RANK     2000016    // u8[1.6M]                    1,600,000
#define WS_BSUM     3600016    // u32[512]                        2,048
#define WS_BOFF     3602064    // u32[512]                        2,048
#define WS_SORTED   3604112    // u32[1.6M]                   6,400,000
#define WS_HB       10004112   // bf16[50000*128]            12,800,000
#define WS_WT       22804112   // bf16[128][1024]               262,144
#define WS_NEEDED   23066256

typedef __attribute__((ext_vector_type(8))) short bf16x8;
typedef __attribute__((ext_vector_type(4))) float f32x4;

__device__ __forceinline__ unsigned short f2bf(float f) {
    unsigned u = __float_as_uint(f);
    return (unsigned short)((u + 0x7fffu + ((u >> 16) & 1u)) >> 16);  // RNE
}
__device__ __forceinline__ float bf2f(unsigned short b) {
    return __uint_as_float((unsigned)b << 16);
}
__device__ __forceinline__ float lo16(unsigned u) { return __uint_as_float(u << 16); }
__device__ __forceinline__ float hi16(unsigned u) { return __uint_as_float(u & 0xffff0000u); }

// zero packed counts (must precede hist)
__global__ void k_zero(unsigned* __restrict__ counts) {
    int i = blockIdx.x * 256 + threadIdx.x;
    if (i < 25000) ((uint4*)counts)[i] = make_uint4(0u, 0u, 0u, 0u);
}

// hist (blocks 0..6249) | h->bf16 cast (6250..9374) | Wcat^T build (9375..9886)
__global__ void k_histprep(const int* __restrict__ dst, const int* __restrict__ et,
                           unsigned* __restrict__ counts, unsigned char* __restrict__ rank,
                           const float* __restrict__ h, unsigned short* __restrict__ hb,
                           const float* __restrict__ W, unsigned short* __restrict__ wt) {
    int b = blockIdx.x, t = threadIdx.x;
    if (b < 6250) {
        int e = b * 256 + t;
        if (e < N_EDGES_C) {
            int key = dst[e] * NREL + et[e];
            int sh = 8 * (key & 3);
            unsigned old = atomicAdd(&counts[key >> 2], 1u << sh);
            rank[e] = (unsigned char)((old >> sh) & 0xffu);
        }
    } else if (b < 6250 + 3125) {
        int i = ((b - 6250) * 256 + t) * 8;
        float4 v0 = *(const float4*)&h[i];
        float4 v1 = *(const float4*)&h[i + 4];
        uint4 o;
        o.x = (unsigned)f2bf(v0.x) | ((unsigned)f2bf(v0.y) << 16);
        o.y = (unsigned)f2bf(v0.z) | ((unsigned)f2bf(v0.w) << 16);
        o.z = (unsigned)f2bf(v1.x) | ((unsigned)f2bf(v1.y) << 16);
        o.w = (unsigned)f2bf(v1.z) | ((unsigned)f2bf(v1.w) << 16);
        *(uint4*)&hb[i] = o;
    } else {
        int i = (b - 9375) * 256 + t;       // 0..131071
        int n = i >> 10, rk = i & 1023;
        wt[i] = f2bf(W[rk * FEAT + n]);     // wt[n*1024 + rk]
    }
}

__global__ void k_scan_a(const unsigned* __restrict__ counts, unsigned* __restrict__ bsum) {
    __shared__ unsigned s[1024];
    int t = threadIdx.x;
    int i = blockIdx.x * 1024 + t;
    unsigned v = 0;
    if (i < NBUCKETS) v = (counts[i >> 2] >> (8 * (i & 3))) & 0xffu;
    s[t] = v;
    __syncthreads();
    for (int o = 512; o > 0; o >>= 1) {
        if (t < o) s[t] += s[t + o];
        __syncthreads();
    }
    if (t == 0) bsum[blockIdx.x] = s[0];
}

__global__ void k_scan_b(const unsigned* __restrict__ bsum, unsigned* __restrict__ boff, int nb) {
    __shared__ unsigned s[512];
    int t = threadIdx.x;
    unsigned v = (t < nb) ? bsum[t] : 0u;
    s[t] = v;
    __syncthreads();
    for (int o = 1; o < 512; o <<= 1) {
        unsigned u = (t >= o) ? s[t - o] : 0u;
        __syncthreads();
        s[t] += u;
        __syncthreads();
    }
    if (t < nb) boff[t] = s[t] - v;
}

__global__ void k_scan_c(const unsigned* __restrict__ counts, const unsigned* __restrict__ boff,
                         unsigned* __restrict__ offsets) {
    __shared__ unsigned s[1024];
    int t = threadIdx.x;
    int i = blockIdx.x * 1024 + t;
    unsigned v = 0;
    if (i < NBUCKETS) v = (counts[i >> 2] >> (8 * (i & 3))) & 0xffu;
    s[t] = v;
    __syncthreads();
    for (int o = 1; o < 1024; o <<= 1) {
        unsigned u = (t >= o) ? s[t - o] : 0u;
        __syncthreads();
        s[t] += u;
        __syncthreads();
    }
    if (i < NBUCKETS) offsets[i] = boff[blockIdx.x] + s[t] - v;
    if (i == NBUCKETS) offsets[i] = N_EDGES_C;   // sentinel
}

// atomic-free scatter of 4B records: (src<<16) | bf16(norm)
__global__ void k_scatter(const int* __restrict__ src, const int* __restrict__ dst,
                          const int* __restrict__ et, const float* __restrict__ norm,
                          const unsigned* __restrict__ offsets,
                          const unsigned char* __restrict__ rank,
                          unsigned* __restrict__ sorted) {
    int e = blockIdx.x * 256 + threadIdx.x;
    if (e < N_EDGES_C) {
        int key = dst[e] * NREL + et[e];
        unsigned pos = offsets[key] + (unsigned)rank[e];
        sorted[pos] = ((unsigned)src[e] << 16) | (unsigned)f2bf(norm[e]);
    }
}

// Fused aggregate+GEMM, TILE=16 nodes/block, 512 threads = 8 waves.
// Wave w owns rows 2w,2w+1 = ONE contiguous 16-bucket record stream.
// 16-deep batches: 16 speculative scalar-base row-gathers in flight, then
// scalar bucket logic on loaded data. Streaming data (sorted reads, out
// stores) is non-temporal so hb keeps maximal L2 residency.
// One barrier, then a single K=1024 MFMA pass (1 col-tile/wave, B from wt).
__global__ __launch_bounds__(512) void k_fused(const unsigned* __restrict__ sorted,
                                               const unsigned* __restrict__ offsets,
                                               const unsigned short* __restrict__ hb,
                                               const unsigned short* __restrict__ wt,
                                               const float* __restrict__ bias,
                                               float* __restrict__ out) {
    __shared__ char At[32768];            // [16 rows][1024 k] bf16, XOR-swizzled
    __shared__ float csLds[TILE][NREL];
    int t = threadIdx.x, w = t >> 6, lane = t & 63;
    int node0 = blockIdx.x * TILE;
    int grp = lane >> 4, ln16 = lane & 15;

    // 17 bucket boundaries (2 rows x 8 rels), lane-parallel
    int kbase = (node0 + 2 * w) * NREL;
    unsigned bnds = offsets[kbase + (lane <= 16 ? lane : 16)];
    unsigned pp   = __shfl(bnds, 0);
    unsigned send = __shfl(bnds, 16);
    int j = 0;
    unsigned bend = (unsigned)__builtin_amdgcn_readlane((int)bnds, 1);
    float a0 = 0.f, a1 = 0.f, cs = 0.f;

#define FLUSHJ(JJ, A0, A1, CS)                                                 \
    do {                                                                       \
        int row_ = 2 * w + ((JJ) >> 3);                                        \
        int jr_  = (JJ) & 7;                                                   \
        *(unsigned*)(At + row_ * 2048 +                                        \
                     ((jr_ * 256 + lane * 4) ^ ((row_ & 7) << 4))) =           \
            (unsigned)f2bf(A0) | ((unsigned)f2bf(A1) << 16);                   \
        if (lane == 0) csLds[row_][jr_] = (CS);                                \
    } while (0)

    {
        unsigned q0 = pp + lane;
        unsigned recv = __builtin_nontemporal_load(
            &sorted[q0 < N_EDGES_C ? q0 : (N_EDGES_C - 1)]);
        unsigned wstart = pp;
        while (wstart < send) {
            unsigned qn = wstart + 64 + lane;
            unsigned recv_n = __builtin_nontemporal_load(
                &sorted[qn < N_EDGES_C ? qn : (N_EDGES_C - 1)]);
#pragma unroll 1
            for (int b = 0; b < 4; b++) {
                // gather phase: 16 speculative row-loads, scalar base addresses
                unsigned hv[16];
                float nvv[16];
#pragma unroll
                for (int u = 0; u < 16; u++) {
                    unsigned ru = (unsigned)__builtin_amdgcn_readlane((int)recv, b * 16 + u);
                    nvv[u] = __uint_as_float((ru & 0xffffu) << 16);
                    const unsigned short* rp = hb + (size_t)(ru >> 16) * FEAT;
                    hv[u] = *(const unsigned*)(rp + lane * 2);
                }
                // consume phase: scalar bucket logic on loaded data
#pragma unroll
                for (int u = 0; u < 16; u++) {
                    unsigned gpos = wstart + (unsigned)(b * 16 + u);
                    if (gpos >= send) goto stream_done;
                    while (gpos >= bend) {       // flush bucket j, advance
                        FLUSHJ(j, a0, a1, cs);
                        a0 = a1 = cs = 0.f;
                        j++;
                        bend = (unsigned)__builtin_amdgcn_readlane(
                            (int)bnds, j < 16 ? j + 1 : 16);
                    }
                    a0 += nvv[u] * lo16(hv[u]);
                    a1 += nvv[u] * hi16(hv[u]);
                    cs += nvv[u];
                }
            }
            wstart += 64;
            recv = recv_n;
        }
    stream_done:;
    }
    // trailing: flush current bucket, then zeros through bucket 15
    while (j < 16) {
        FLUSHJ(j, a0, a1, cs);
        a0 = a1 = cs = 0.f;
        j++;
    }
#undef FLUSHJ
    __syncthreads();

    // ---- single MFMA pass: K=1024, wave w covers cols [w*16, w*16+16) ----
    f32x4 acc = (f32x4){0.f, 0.f, 0.f, 0.f};
    const unsigned short* wcol = wt + (size_t)(w * 16 + ln16) * KTOT + grp * 8;
#pragma unroll 8
    for (int ks = 0; ks < 32; ks++) {
        bf16x8 af = *(const bf16x8*)(At + ln16 * 2048 +
                                     ((ks * 64 + grp * 16) ^ ((ln16 & 7) << 4)));
        bf16x8 bf = *(const bf16x8*)(wcol + ks * 32);
        acc = __builtin_amdgcn_mfma_f32_16x16x32_bf16(af, bf, acc, 0, 0, 0);
    }

    // ---- epilogue: bias via csum + ReLU. D map: col=lane&15, row=(lane>>4)*4+reg
#pragma unroll
    for (int i = 0; i < 4; i++) {
        int rl = grp * 4 + i;
        int g  = node0 + rl;
        int col = w * 16 + ln16;
        float v = acc[i];
#pragma unroll
        for (int rr = 0; rr < NREL; rr++) v += csLds[rl][rr] * bias[rr * FEAT + col];
        __builtin_nontemporal_store(fmaxf(v, 0.f), &out[(size_t)g * FEAT + col]);
    }
}

extern "C" void kernel_launch(void* const* d_in, const int* in_sizes, int n_in,
                              void* d_out, int out_size, void* d_ws, size_t ws_size,
                              hipStream_t stream) {
    const float* h    = (const float*)d_in[0];
    const int*   src  = (const int*)d_in[1];
    const int*   dst  = (const int*)d_in[2];
    const int*   et   = (const int*)d_in[3];
    const float* norm = (const float*)d_in[4];
    const float* W    = (const float*)d_in[5];
    const float* b    = (const float*)d_in[6];
    float*       out  = (float*)d_out;

    if (ws_size < (size_t)WS_NEEDED) return;

    char* ws = (char*)d_ws;
    unsigned*       counts  = (unsigned*)(ws + WS_COUNTS);
    unsigned*       offsets = (unsigned*)(ws + WS_OFFSETS);
    unsigned char*  rank    = (unsigned char*)(ws + WS_RANK);
    unsigned*       bsum    = (unsigned*)(ws + WS_BSUM);
    unsigned*       boff    = (unsigned*)(ws + WS_BOFF);
    unsigned*       sorted  = (unsigned*)(ws + WS_SORTED);
    unsigned short* hb      = (unsigned short*)(ws + WS_HB);
    unsigned short* wt      = (unsigned short*)(ws + WS_WT);

    int nb = (NBUCKETS + 1023) / 1024;   // 391

    k_zero<<<98, 256, 0, stream>>>(counts);
    k_histprep<<<6250 + 3125 + 512, 256, 0, stream>>>(dst, et, counts, rank,
                                                      h, hb, W, wt);
    k_scan_a<<<nb, 1024, 0, stream>>>(counts, bsum);
    k_scan_b<<<1, 512, 0, stream>>>(bsum, boff, nb);
    k_scan_c<<<nb, 1024, 0, stream>>>(counts, boff, offsets);
    k_scatter<<<6250, 256, 0, stream>>>(src, dst, et, norm, offsets, rank, sorted);

    k_fused<<<N_NODES_C / TILE, 512, 0, stream>>>(sorted, offsets, hb, wt, b, out);
}